// Round 1
// baseline (58281.921 us; speedup 1.0000x reference)
//
#include <hip/hip_runtime.h>
#include <stdint.h>

// LSTM seq2seq (B=64, S=2048, H=512, L=2) as ONE persistent kernel.
// 128 WGs x 256 thr; WG w owns hidden cols [4w,4w+4) -> gate rows {4w+r+512q}.
// Grid barrier: padded arrive flags + WG0 gather + go flag (device scope).
// Matmuls: mfma_f32_16x16x32_f16, weights LDS-resident in B-frag order.
// c-state fp32 in LDS (never rounded); only h passes through fp16.

#define NWG   128
#define NTHR  256
#define SEQ   2048
#define NB    64
#define NH    512

typedef _Float16 half8v __attribute__((ext_vector_type(8)));
typedef float    f32x4  __attribute__((ext_vector_type(4)));

struct P {
  const float *x;
  const float *eWih0, *eWhh0, *ebih0, *ebhh0;
  const float *eWih1, *eWhh1, *ebih1, *ebhh1;
  const float *dWih0, *dWhh0, *dbih0, *dbhh0;
  const float *dWih1, *dWhh1, *dbih1, *dbhh1;
  const float *fcW, *fcb;
  float *out;
  unsigned short *H0, *H1;        // each: 2 parities x [128 kb][64 b][4 kk] fp16 (stride 32768 halfs)
  unsigned int *arrive, *go;      // arrive: [4 slot][128 wg] padded 128B; go: [4 slot] padded 128B
};

__device__ __forceinline__ float sigf(float v)   { return 1.f / (1.f + __expf(-v)); }
__device__ __forceinline__ float tanh_f(float v) { return 2.f * sigf(2.f * v) - 1.f; }

__global__ __launch_bounds__(NTHR) void lstm_persist(P p) {
  __shared__ half8v wlds[3][16][64];   // 48KB: 3 matrices, B-frag order [ks][lane][8]
  __shared__ float  bias_lds[4][16];   // e0,e1,d0,d1 (bih+bhh), per-WG n order
  __shared__ float  w0v_lds[2][16];    // Wih0 col (enc,dec), per-WG n order
  __shared__ float  fcW_lds[NH];
  __shared__ float  c_lds[2][NB][4];   // fp32 cell state [layer][b][local hcol]
  __shared__ float  y_lds[NB];
  __shared__ float  psum[4][NB];
  __shared__ float  fcb_s;

  const int wg   = blockIdx.x;
  const int tid  = threadIdx.x;
  const int lane = tid & 63;
  const int wv   = tid >> 6;      // wave id: batch block
  const int Mb   = wv * 16;
  const int lo4  = lane >> 4;
  const int nn   = lane & 15;     // n: (q=nn>>2 gate type, r=nn&3 local hcol)

  unsigned int epoch = 0;

  // ---------------- grid barrier ----------------
  auto gbar = [&]() {
    epoch++;
    const unsigned int slot = epoch & 3u;
    __syncthreads();                              // drains this WG's stores to L2
    if (wg == 0) {
      if (tid == 0) __threadfence();              // writeback L2 -> LLC (release)
      if (tid >= 1 && tid < NWG) {
        while (__hip_atomic_load(p.arrive + ((size_t)slot * NWG + tid) * 32,
                                 __ATOMIC_RELAXED, __HIP_MEMORY_SCOPE_AGENT) != epoch) {}
      }
      __syncthreads();
      if (tid == 0) {
        __builtin_amdgcn_fence(__ATOMIC_ACQUIRE, "agent");
        __hip_atomic_store(p.go + slot * 32, epoch,
                           __ATOMIC_RELEASE, __HIP_MEMORY_SCOPE_AGENT);
      }
    } else {
      if (tid == 0) {
        __threadfence();                          // release my writes
        __hip_atomic_store(p.arrive + ((size_t)slot * NWG + wg) * 32, epoch,
                           __ATOMIC_RELAXED, __HIP_MEMORY_SCOPE_AGENT);
        while (__hip_atomic_load(p.go + slot * 32,
                                 __ATOMIC_RELAXED, __HIP_MEMORY_SCOPE_AGENT) != epoch) {}
        __builtin_amdgcn_fence(__ATOMIC_ACQUIRE, "agent");
      }
    }
    __syncthreads();
  };

  // ---------------- weight gather: global fp32 -> LDS fp16 B-frags ----------------
  auto loadW = [&](int slot, const float *__restrict__ W) {
    for (int idx = tid; idx < 16 * 64; idx += NTHR) {
      const int ks = idx >> 6, l = idx & 63;
      const int g = 4 * wg + (l & 3) + 512 * ((l >> 2) & 3);  // gate row for n=l&15
      const float *base = W + (size_t)g * NH + 32 * ks + 4 * (l >> 4);
      f32x4 wa, wb;
      __builtin_memcpy(&wa, base, 16);
      __builtin_memcpy(&wb, base + 16, 16);
      half8v h;
      h[0] = (_Float16)wa[0]; h[1] = (_Float16)wa[1];
      h[2] = (_Float16)wa[2]; h[3] = (_Float16)wa[3];
      h[4] = (_Float16)wb[0]; h[5] = (_Float16)wb[1];
      h[6] = (_Float16)wb[2]; h[7] = (_Float16)wb[3];
      wlds[slot][ks][l] = h;
    }
  };

  // ---------------- G += Hstate @ W^T for this WG's 16 gate rows ----------------
  auto mm_acc = [&](f32x4 &acc, const unsigned short *__restrict__ Hbuf, int slot) {
    const unsigned short *pa = Hbuf + (Mb + nn) * 4;   // A: m = lane&15 = batch
#pragma unroll
    for (int ks = 0; ks < 16; ++ks) {
      const int kb = 8 * ks + lo4;
      union { uint64_t u[2]; half8v h; } A;
      __builtin_memcpy(&A.u[0], pa + kb * 256, 8);         // k = 32ks+4*lo4+[0..3]
      __builtin_memcpy(&A.u[1], pa + (kb + 4) * 256, 8);   // k = +16
      acc = __builtin_amdgcn_mfma_f32_16x16x32_f16(A.h, wlds[slot][ks][lane], acc, 0, 0, 0);
    }
  };

  // ---------------- gates -> (c,h) update; write h' fp16 to Hw ----------------
  auto cell = [&](const f32x4 &acc, const float *bias16, const float *w016,
                  const float *xv4, unsigned short *Hw, float *cl) {
    const int q = nn >> 2, r = nn & 3;
    float v[4];
#pragma unroll
    for (int j = 0; j < 4; ++j) {
      const float g = acc[j] + bias16[nn] + xv4[j] * w016[nn];
      v[j] = (q == 2) ? tanh_f(g) : sigf(g);   // g-gate tanh, i/f/o sigmoid
    }
    float s4[4], s8[4], s12[4];
#pragma unroll
    for (int j = 0; j < 4; ++j) {
      s4[j]  = __shfl_xor(v[j], 4, 64);
      s8[j]  = __shfl_xor(v[j], 8, 64);
      s12[j] = __shfl_xor(v[j], 12, 64);
    }
    if (q == 0) {                      // owner lanes: have (i,f,g,o) = (v,s4,s8,s12)
#pragma unroll
      for (int j = 0; j < 4; ++j) {
        const int b = Mb + 4 * lo4 + j;
        const float co = cl[b * 4 + r];
        const float cn = s4[j] * co + v[j] * s8[j];
        const float hn = s12[j] * tanh_f(cn);
        cl[b * 4 + r] = cn;
        union { _Float16 f; unsigned short u; } cv;
        cv.f = (_Float16)hn;
        Hw[wg * 256 + b * 4 + r] = cv.u;   // kb=wg, kk=r  (matches A layout)
      }
    }
  };

  // ---------------- y = fc(h1'): redundant per WG; WG0 writes out ----------------
  auto do_fc = [&](const unsigned short *__restrict__ Hr, int outT, bool wr) {
    const int b = tid & 63, part = tid >> 6;
    float s = 0.f;
#pragma unroll 8
    for (int kb = part * 32; kb < part * 32 + 32; ++kb) {
      union { uint64_t u; _Float16 h[4]; } cv;
      __builtin_memcpy(&cv.u, Hr + kb * 256 + b * 4, 8);
      const float *fw = fcW_lds + kb * 4;
      s += (float)cv.h[0] * fw[0] + (float)cv.h[1] * fw[1]
         + (float)cv.h[2] * fw[2] + (float)cv.h[3] * fw[3];
    }
    psum[part][b] = s;
    __syncthreads();
    if (tid < NB) {
      const float y = psum[0][tid] + psum[1][tid] + psum[2][tid] + psum[3][tid] + fcb_s;
      y_lds[tid] = y;
      if (wr) p.out[(size_t)tid * SEQ + outT] = y;
    }
    __syncthreads();
  };

  // ================= init =================
  loadW(0, p.eWhh0); loadW(1, p.eWih1); loadW(2, p.eWhh1);
  if (tid < 16) {
    const int g = 4 * wg + (tid & 3) + 512 * (tid >> 2);
    bias_lds[0][tid] = p.ebih0[g] + p.ebhh0[g];
    bias_lds[1][tid] = p.ebih1[g] + p.ebhh1[g];
    bias_lds[2][tid] = p.dbih0[g] + p.dbhh0[g];
    bias_lds[3][tid] = p.dbih1[g] + p.dbhh1[g];
    w0v_lds[0][tid] = p.eWih0[g];
    w0v_lds[1][tid] = p.dWih0[g];
  }
  for (int k = tid; k < NH; k += NTHR) fcW_lds[k] = p.fcW[k];
  if (tid == 0) fcb_s = p.fcb[0];
  for (int i = tid; i < 2 * NB * 4; i += NTHR) (&c_lds[0][0][0])[i] = 0.f;
  if (tid < NB) y_lds[tid] = 0.f;
  if (tid < 64) {
    const uint64_t z = 0;
#pragma unroll
    for (int par = 0; par < 2; ++par) {
      __builtin_memcpy(p.H0 + par * 32768 + wg * 256 + tid * 4, &z, 8);
      __builtin_memcpy(p.H1 + par * 32768 + wg * 256 + tid * 4, &z, 8);
    }
  }
  gbar();

  // ================= encoder: pipelined L0(t) || L1(t-1), 1 barrier/step ========
  for (int t = 0; t <= SEQ; ++t) {
    const int ri = (t + 1) & 1, wi = t & 1;
    if (t < SEQ) {                                   // L0(t)
      float xv[4];
#pragma unroll
      for (int j = 0; j < 4; ++j) xv[j] = p.x[(size_t)(Mb + 4 * lo4 + j) * SEQ + t];
      f32x4 acc = {0.f, 0.f, 0.f, 0.f};
      mm_acc(acc, p.H0 + ri * 32768, 0);             // Whh0 . h0(t-1)
      cell(acc, bias_lds[0], w0v_lds[0], xv, p.H0 + wi * 32768, &c_lds[0][0][0]);
    }
    if (t > 0) {                                     // L1(t-1)
      const float zv[4] = {0.f, 0.f, 0.f, 0.f};
      f32x4 acc = {0.f, 0.f, 0.f, 0.f};
      mm_acc(acc, p.H0 + ri * 32768, 1);             // Wih1 . h0'(t-1)
      mm_acc(acc, p.H1 + ri * 32768, 2);             // Whh1 . h1(t-2)
      cell(acc, bias_lds[1], w0v_lds[0], zv, p.H1 + wi * 32768, &c_lds[1][0][0]);
    }
    gbar();
  }

  // ================= enc -> dec transition =================
  loadW(0, p.dWhh0); loadW(1, p.dWih1); loadW(2, p.dWhh1);
  if (tid < NB) y_lds[tid] = 0.f;
  __syncthreads();

  // ================= decoder: 2 barriers/step =================
  for (int t = 0; t < SEQ; ++t) {
    const int r0 = (t ^ 1) & 1, w0 = t & 1;     // H0 parities
    const int r1 = t & 1,       w1 = (t ^ 1) & 1; // H1 parities
    if (t > 0) do_fc(p.H1 + r1 * 32768, t - 1, wg == 0);  // y(t-1) = fc(h1'(t-1))
    {                                                      // L0(t)
      float yv[4];
#pragma unroll
      for (int j = 0; j < 4; ++j) yv[j] = y_lds[Mb + 4 * lo4 + j];
      f32x4 acc = {0.f, 0.f, 0.f, 0.f};
      mm_acc(acc, p.H0 + r0 * 32768, 0);          // Whh0 . h0(t-1)
      cell(acc, bias_lds[2], w0v_lds[1], yv, p.H0 + w0 * 32768, &c_lds[0][0][0]);
    }
    gbar();
    {                                             // L1(t)
      const float zv[4] = {0.f, 0.f, 0.f, 0.f};
      f32x4 acc = {0.f, 0.f, 0.f, 0.f};
      mm_acc(acc, p.H0 + w0 * 32768, 1);          // Wih1 . h0'(t)
      mm_acc(acc, p.H1 + r1 * 32768, 2);          // Whh1 . h1(t-1)
      cell(acc, bias_lds[3], w0v_lds[1], zv, p.H1 + w1 * 32768, &c_lds[1][0][0]);
    }
    gbar();
  }
  // final output y(2047): h1'(2047) sits in H1 parity 0
  if (wg == 0) do_fc(p.H1 + 0, SEQ - 1, true);
}

extern "C" void kernel_launch(void* const* d_in, const int* in_sizes, int n_in,
                              void* d_out, int out_size, void* d_ws, size_t ws_size,
                              hipStream_t stream) {
  (void)in_sizes; (void)n_in; (void)out_size; (void)ws_size;
  P p;
  p.x     = (const float*)d_in[0];
  p.eWih0 = (const float*)d_in[1];  p.eWhh0 = (const float*)d_in[2];
  p.ebih0 = (const float*)d_in[3];  p.ebhh0 = (const float*)d_in[4];
  p.eWih1 = (const float*)d_in[5];  p.eWhh1 = (const float*)d_in[6];
  p.ebih1 = (const float*)d_in[7];  p.ebhh1 = (const float*)d_in[8];
  p.dWih0 = (const float*)d_in[9];  p.dWhh0 = (const float*)d_in[10];
  p.dbih0 = (const float*)d_in[11]; p.dbhh0 = (const float*)d_in[12];
  p.dWih1 = (const float*)d_in[13]; p.dWhh1 = (const float*)d_in[14];
  p.dbih1 = (const float*)d_in[15]; p.dbhh1 = (const float*)d_in[16];
  p.fcW   = (const float*)d_in[17]; p.fcb   = (const float*)d_in[18];
  p.out   = (float*)d_out;

  p.H0 = (unsigned short*)d_ws;                       // 2*32768 halfs = 128KB
  p.H1 = (unsigned short*)d_ws + 2 * 32768;           // 128KB
  p.arrive = (unsigned int*)((char*)d_ws + 262144);   // 64KB (4 slots x 128 WGs x 128B)
  p.go     = (unsigned int*)((char*)d_ws + 262144 + 65536);  // 512B

  lstm_persist<<<dim3(NWG), dim3(NTHR), 0, stream>>>(p);
}

// Round 2
// 38130.487 us; speedup vs baseline: 1.5285x; 1.5285x over previous
//
#include <hip/hip_runtime.h>
#include <stdint.h>

// LSTM seq2seq (B=64, S=2048, H=512, L=2) as ONE persistent kernel, v2.
// 128 WGs x 256 thr; WG w owns hidden cols [4w,4w+4) -> gate rows {4w+r+512q}.
// v2: flat 1-hop barrier (2-slot equality, replay-safe), all cross-WG data via
// agent-scope atomics (no per-phase L2 wb/inv), staged A-frag loads, fc as
// distributed atomicAdd partials, decoder phase-A matmul hoisted into phase B.

#define NWG   128
#define NTHR  256
#define SEQ   2048
#define NB    64
#define NH    512

typedef _Float16 half8v __attribute__((ext_vector_type(8)));
typedef float    f32x4  __attribute__((ext_vector_type(4)));

struct P {
  const float *x;
  const float *eWih0, *eWhh0, *ebih0, *ebhh0;
  const float *eWih1, *eWhh1, *ebih1, *ebhh1;
  const float *dWih0, *dWhh0, *dbih0, *dbhh0;
  const float *dWih1, *dWhh1, *dbih1, *dbhh1;
  const float *fcW, *fcb;
  float *out;
  unsigned short *H0, *H1;   // each: 2 parities x [128 kb][64 b][4 kk] fp16 (stride 32768 halfs)
  float *yAcc;               // [2 slot][64 b][16 pad] floats
  unsigned *arrive;          // [2 slot][128 wg][4 pad] uints
};

__device__ __forceinline__ uint64_t ldg64(const uint64_t* p) {
  return __hip_atomic_load(p, __ATOMIC_RELAXED, __HIP_MEMORY_SCOPE_AGENT);
}
__device__ __forceinline__ void stg64(uint64_t* p, uint64_t v) {
  __hip_atomic_store(p, v, __ATOMIC_RELAXED, __HIP_MEMORY_SCOPE_AGENT);
}
__device__ __forceinline__ float ldgf(const float* p) {
  return __hip_atomic_load(p, __ATOMIC_RELAXED, __HIP_MEMORY_SCOPE_AGENT);
}
__device__ __forceinline__ void stgf(float* p, float v) {
  __hip_atomic_store(p, v, __ATOMIC_RELAXED, __HIP_MEMORY_SCOPE_AGENT);
}
__device__ __forceinline__ float sigf(float v)   { return 1.f / (1.f + __expf(-v)); }
__device__ __forceinline__ float tanhf_(float v) { return 2.f * sigf(2.f * v) - 1.f; }

__global__ __launch_bounds__(NTHR, 1) void lstm_persist(P p) {
  __shared__ half8v wlds[3][16][64];   // 48KB: slot0=Whh0, slot1=Wih1, slot2=Whh1
  __shared__ float  bias_lds[4][16];   // e0,e1,d0,d1 (bih+bhh)
  __shared__ float  w0v_lds[2][16];    // Wih0 col (enc,dec)
  __shared__ float  fcw4[4];           // fcW for this WG's 4 cols
  __shared__ float  c_lds[2][NB][4];   // fp32 cell state
  __shared__ float  h_tmp[2][NB][4];   // fp32 h' staging (L0, L1)
  __shared__ float  yv_s[NB];
  __shared__ float  fcb_s;

  const int wg   = blockIdx.x;
  const int tid  = threadIdx.x;
  const int lane = tid & 63;
  const int wv   = tid >> 6;
  const int Mb   = wv * 16;
  const int lo4  = lane >> 4;
  const int nn   = lane & 15;
  const int q    = nn >> 2, r = nn & 3;

  unsigned epoch = 0;

  // ---------------- flat 1-hop grid barrier ----------------
  auto gbar = [&]() {
    epoch++;
    __syncthreads();                      // drains all waves' vmem (stores complete)
    if (tid == 0)
      __hip_atomic_store(p.arrive + ((epoch & 1u) * NWG + wg) * 4, epoch,
                         __ATOMIC_RELEASE, __HIP_MEMORY_SCOPE_AGENT);
    if (tid < 64) {
      const unsigned* fa = p.arrive + ((epoch & 1u) * NWG + tid) * 4;
      const unsigned* fb = fa + 64 * 4;
      bool da = false, db = false;
      do {
        if (!da) da = (__hip_atomic_load(fa, __ATOMIC_RELAXED, __HIP_MEMORY_SCOPE_AGENT) == epoch);
        if (!db) db = (__hip_atomic_load(fb, __ATOMIC_RELAXED, __HIP_MEMORY_SCOPE_AGENT) == epoch);
      } while (!(da && db));
    }
    __builtin_amdgcn_fence(__ATOMIC_ACQUIRE, "workgroup");  // compiler/order fence (no L2 inv)
    __syncthreads();
  };

  // ---------------- weight gather: global fp32 -> LDS fp16 B-frags ----------------
  auto loadW = [&](int slot, const float *__restrict__ W) {
    for (int idx = tid; idx < 16 * 64; idx += NTHR) {
      const int ks = idx >> 6, l = idx & 63;
      const int g = 4 * wg + (l & 3) + 512 * ((l >> 2) & 3);
      const float *base = W + (size_t)g * NH + 32 * ks + 4 * (l >> 4);
      f32x4 wa, wb;
      __builtin_memcpy(&wa, base, 16);
      __builtin_memcpy(&wb, base + 16, 16);
      half8v h;
      h[0] = (_Float16)wa[0]; h[1] = (_Float16)wa[1];
      h[2] = (_Float16)wa[2]; h[3] = (_Float16)wa[3];
      h[4] = (_Float16)wb[0]; h[5] = (_Float16)wb[1];
      h[6] = (_Float16)wb[2]; h[7] = (_Float16)wb[3];
      wlds[slot][ks][l] = h;
    }
  };

  // ---- phase matmul: stage ALL loads, then MFMA. acc0<-slot0, acc1<-slot1(+slot2 on Hb1) ----
  auto mm_phase = [&](f32x4 &acc0, f32x4 &acc1, const unsigned short* Hb0,
                      const unsigned short* Hb1, bool d0, bool d1, bool dH1) {
    const uint64_t* b0 = (const uint64_t*)Hb0 + (Mb + nn);
    const uint64_t* b1 = (const uint64_t*)Hb1 + (Mb + nn);
    uint64_t a0[32], a1[32];
#pragma unroll
    for (int ks = 0; ks < 16; ++ks) {
      const int kb = 8 * ks + lo4;
      a0[2 * ks]     = ldg64(b0 + kb * 64);
      a0[2 * ks + 1] = ldg64(b0 + kb * 64 + 256);
    }
    if (dH1) {
#pragma unroll
      for (int ks = 0; ks < 16; ++ks) {
        const int kb = 8 * ks + lo4;
        a1[2 * ks]     = ldg64(b1 + kb * 64);
        a1[2 * ks + 1] = ldg64(b1 + kb * 64 + 256);
      }
    }
#pragma unroll
    for (int ks = 0; ks < 16; ++ks) {
      union { uint64_t u[2]; half8v h; } A;
      A.u[0] = a0[2 * ks]; A.u[1] = a0[2 * ks + 1];
      if (d0) acc0 = __builtin_amdgcn_mfma_f32_16x16x32_f16(A.h, wlds[0][ks][lane], acc0, 0, 0, 0);
      if (d1) acc1 = __builtin_amdgcn_mfma_f32_16x16x32_f16(A.h, wlds[1][ks][lane], acc1, 0, 0, 0);
    }
    if (dH1) {
#pragma unroll
      for (int ks = 0; ks < 16; ++ks) {
        union { uint64_t u[2]; half8v h; } A;
        A.u[0] = a1[2 * ks]; A.u[1] = a1[2 * ks + 1];
        acc1 = __builtin_amdgcn_mfma_f32_16x16x32_f16(A.h, wlds[2][ks][lane], acc1, 0, 0, 0);
      }
    }
  };

  // ---------------- gates -> (c,h'); h' fp32 into h_tmp[sel] ----------------
  auto cell = [&](const f32x4 &acc, const float* bias16, const float* w016,
                  const float* xv4, int sel, float* cl) {
    float v[4];
#pragma unroll
    for (int j = 0; j < 4; ++j) {
      const float g = acc[j] + bias16[nn] + xv4[j] * w016[nn];
      v[j] = (q == 2) ? tanhf_(g) : sigf(g);
    }
    float s4[4], s8[4], s12[4];
#pragma unroll
    for (int j = 0; j < 4; ++j) {
      s4[j]  = __shfl_xor(v[j], 4, 64);
      s8[j]  = __shfl_xor(v[j], 8, 64);
      s12[j] = __shfl_xor(v[j], 12, 64);
    }
    if (q == 0) {
#pragma unroll
      for (int j = 0; j < 4; ++j) {
        const int b = Mb + 4 * lo4 + j;
        const float co = cl[b * 4 + r];
        const float cn = s4[j] * co + v[j] * s8[j];
        cl[b * 4 + r] = cn;
        h_tmp[sel][b][r] = s12[j] * tanhf_(cn);
      }
    }
  };

  auto packrow = [&](int sel, int b) -> uint64_t {
    union { uint64_t u; _Float16 h[4]; } cv;
#pragma unroll
    for (int k = 0; k < 4; ++k) cv.h[k] = (_Float16)h_tmp[sel][b][k];
    return cv.u;
  };

  // ================= init =================
  loadW(0, p.eWhh0); loadW(1, p.eWih1); loadW(2, p.eWhh1);
  if (tid < 16) {
    const int g = 4 * wg + (tid & 3) + 512 * (tid >> 2);
    bias_lds[0][tid] = p.ebih0[g] + p.ebhh0[g];
    bias_lds[1][tid] = p.ebih1[g] + p.ebhh1[g];
    bias_lds[2][tid] = p.dbih0[g] + p.dbhh0[g];
    bias_lds[3][tid] = p.dbih1[g] + p.dbhh1[g];
    w0v_lds[0][tid] = p.eWih0[g];
    w0v_lds[1][tid] = p.dWih0[g];
  }
  if (tid < 4)  fcw4[tid] = p.fcW[4 * wg + tid];
  if (tid == 0) fcb_s = p.fcb[0];
  for (int i = tid; i < 2 * NB * 4; i += NTHR) (&c_lds[0][0][0])[i] = 0.f;
  if (tid < NB) {
    stg64((uint64_t*)(p.H0 + 32768) + wg * 64 + tid, 0ull);  // h0(-1)=0, parity 1
    stg64((uint64_t*)p.H1 + wg * 64 + tid, 0ull);            // h1(-1)=0, parity 0
  }
  float xv[4];
#pragma unroll
  for (int j = 0; j < 4; ++j) xv[j] = p.x[(size_t)(Mb + 4 * lo4 + j) * SEQ];
  const float zv4[4] = {0.f, 0.f, 0.f, 0.f};
  gbar();

  // ================= encoder: L0(t) || L1(t-1), 1 barrier/phase =================
  for (int t = 0; t <= SEQ; ++t) {
    const int ri = (t + 1) & 1, wi = t & 1;
    const bool d0 = (t < SEQ), d1 = (t > 0);
    f32x4 aL0 = {0.f, 0.f, 0.f, 0.f}, aL1 = {0.f, 0.f, 0.f, 0.f};
    mm_phase(aL0, aL1, p.H0 + ri * 32768, p.H1 + ri * 32768, d0, d1, d1);
    if (d0) cell(aL0, bias_lds[0], w0v_lds[0], xv, 0, &c_lds[0][0][0]);
    if (d1) cell(aL1, bias_lds[1], w0v_lds[0], zv4, 1, &c_lds[1][0][0]);
    if (t + 1 < SEQ) {
#pragma unroll
      for (int j = 0; j < 4; ++j) xv[j] = p.x[(size_t)(Mb + 4 * lo4 + j) * SEQ + (t + 1)];
    }
    __syncthreads();
    if (tid < NB) {
      if (d0) stg64((uint64_t*)(p.H0 + wi * 32768) + wg * 64 + tid, packrow(0, tid));
      if (d1) stg64((uint64_t*)(p.H1 + wi * 32768) + wg * 64 + tid, packrow(1, tid));
    }
    gbar();
  }

  // ================= enc -> dec transition =================
  loadW(0, p.dWhh0); loadW(1, p.dWih1); loadW(2, p.dWhh1);
  __syncthreads();
  f32x4 accPre = {0.f, 0.f, 0.f, 0.f};
  { f32x4 dmy = {0.f, 0.f, 0.f, 0.f};
    mm_phase(accPre, dmy, p.H0 + 32768, p.H1, true, false, false); }  // dWhh0 . h0_enc(2047)
  if (wg == 0 && tid < NB) { stgf(p.yAcc + tid * 16, 0.f); stgf(p.yAcc + 1024 + tid * 16, 0.f); }
  gbar();

  // ================= decoder: A = elementwise only, B = all matmuls =================
  for (int t = 0; t < SEQ; ++t) {
    const int w0p = t & 1;            // H0 parity written by A(t), read by B(t)
    const int r1p = t & 1;            // H1 parity read by B(t)   (h1(t-1))
    const int w1p = (t + 1) & 1;      // H1 parity written by B(t)
    const int ys  = (t ^ 1) & 1;      // y slot read by A(t)      (y(t-1))
    // ---- A(t): y feedback + L0 cell (accPre holds Whh0.h0(t-1)) ----
    if (tid < NB) {
      float yb = 0.f;
      if (t > 0) {
        yb = ldgf(p.yAcc + ys * 1024 + tid * 16) + fcb_s;
        if (wg == 0) p.out[(size_t)tid * SEQ + (t - 1)] = yb;
      }
      yv_s[tid] = yb;
    }
    __syncthreads();
    float yv4[4];
#pragma unroll
    for (int j = 0; j < 4; ++j) yv4[j] = yv_s[Mb + 4 * lo4 + j];
    cell(accPre, bias_lds[2], w0v_lds[1], yv4, 0, &c_lds[0][0][0]);
    __syncthreads();
    if (tid < NB) stg64((uint64_t*)(p.H0 + w0p * 32768) + wg * 64 + tid, packrow(0, tid));
    gbar();
    // ---- B(t): L1(t) + precompute Whh0.h0(t) + fc partial ----
    f32x4 aP = {0.f, 0.f, 0.f, 0.f}, aL1 = {0.f, 0.f, 0.f, 0.f};
    mm_phase(aP, aL1, p.H0 + w0p * 32768, p.H1 + r1p * 32768, true, true, true);
    accPre = aP;
    cell(aL1, bias_lds[3], w0v_lds[1], zv4, 1, &c_lds[1][0][0]);
    __syncthreads();
    if (tid < NB) {
      stg64((uint64_t*)(p.H1 + w1p * 32768) + wg * 64 + tid, packrow(1, tid));
      const float partial = h_tmp[1][tid][0] * fcw4[0] + h_tmp[1][tid][1] * fcw4[1]
                          + h_tmp[1][tid][2] * fcw4[2] + h_tmp[1][tid][3] * fcw4[3];
      atomicAdd(p.yAcc + (t & 1) * 1024 + tid * 16, partial);
      if (wg == 0) stgf(p.yAcc + ((t & 1) ^ 1) * 1024 + tid * 16, 0.f);
    }
    gbar();
  }
  // final output y(2047) from slot 1
  if (wg == 0 && tid < NB)
    p.out[(size_t)tid * SEQ + (SEQ - 1)] = ldgf(p.yAcc + 1024 + tid * 16) + fcb_s;
}

extern "C" void kernel_launch(void* const* d_in, const int* in_sizes, int n_in,
                              void* d_out, int out_size, void* d_ws, size_t ws_size,
                              hipStream_t stream) {
  (void)in_sizes; (void)n_in; (void)out_size; (void)ws_size;
  P p;
  p.x     = (const float*)d_in[0];
  p.eWih0 = (const float*)d_in[1];  p.eWhh0 = (const float*)d_in[2];
  p.ebih0 = (const float*)d_in[3];  p.ebhh0 = (const float*)d_in[4];
  p.eWih1 = (const float*)d_in[5];  p.eWhh1 = (const float*)d_in[6];
  p.ebih1 = (const float*)d_in[7];  p.ebhh1 = (const float*)d_in[8];
  p.dWih0 = (const float*)d_in[9];  p.dWhh0 = (const float*)d_in[10];
  p.dbih0 = (const float*)d_in[11]; p.dbhh0 = (const float*)d_in[12];
  p.dWih1 = (const float*)d_in[13]; p.dWhh1 = (const float*)d_in[14];
  p.dbih1 = (const float*)d_in[15]; p.dbhh1 = (const float*)d_in[16];
  p.fcW   = (const float*)d_in[17]; p.fcb   = (const float*)d_in[18];
  p.out   = (float*)d_out;

  p.H0     = (unsigned short*)d_ws;                          // 128 KB (2 parities)
  p.H1     = (unsigned short*)d_ws + 2 * 32768;              // 128 KB
  p.arrive = (unsigned*)((char*)d_ws + 262144);              // 4 KB
  p.yAcc   = (float*)((char*)d_ws + 262144 + 4096);          // 8 KB

  lstm_persist<<<dim3(NWG), dim3(NTHR), 0, stream>>>(p);
}